// Round 7
// baseline (952.312 us; speedup 1.0000x reference)
//
#include <hip/hip_runtime.h>

typedef unsigned short u16;
typedef __bf16 v8bf __attribute__((ext_vector_type(8)));
typedef unsigned short u16x8 __attribute__((ext_vector_type(8)));
typedef float v4f __attribute__((ext_vector_type(4)));

#define DEV __device__ __forceinline__

constexpr int M_TOK = 512 * 77;   // 39424 = 128*308

DEV u16 f2bf(float f) {
  union { float f; unsigned int u; } v; v.f = f;
  unsigned int r = v.u + 0x7fffu + ((v.u >> 16) & 1u);
  return (u16)(r >> 16);
}

DEV void gload16(const void* g, void* l) {
  __builtin_amdgcn_global_load_lds((const __attribute__((address_space(1))) void*)g,
                                   (__attribute__((address_space(3))) void*)l, 16, 0, 0);
}

DEV v4f MF(v8bf a, v8bf b, v4f c) {
  return __builtin_amdgcn_mfma_f32_16x16x32_bf16(a, b, c, 0, 0, 0);
}

// ---------------- fp32 -> bf16 convert (x4 vectorized), optional scale ----------------
__global__ void cvt4_k(const float* __restrict__ src, u16* __restrict__ dst, int n4, float scale) {
  int i = blockIdx.x * blockDim.x + threadIdx.x;
  if (i >= n4) return;
  const float4 v = ((const float4*)src)[i];
  ushort4 o;
  o.x = f2bf(v.x * scale); o.y = f2bf(v.y * scale);
  o.z = f2bf(v.z * scale); o.w = f2bf(v.w * scale);
  ((ushort4*)dst)[i] = o;
}

__global__ void qkvb_k(const float* __restrict__ qb, const float* __restrict__ kb,
                       const float* __restrict__ vb, float* __restrict__ dst) {
  int i = blockIdx.x * 256 + threadIdx.x;
  if (i >= 2304) return;
  dst[i] = (i < 768) ? qb[i] * 0.125f : (i < 1536 ? kb[i - 768] : vb[i - 1536]);
}

// ---------------- LayerNorm: one wave per row of 768, writes bf16 ----------------
__global__ __launch_bounds__(256) void ln_k(const float* __restrict__ x, const float* __restrict__ w,
                                            const float* __restrict__ bvec, u16* __restrict__ out, int nrows) {
  const int lane = threadIdx.x & 63;
  const int row = blockIdx.x * 4 + (threadIdx.x >> 6);
  if (row >= nrows) return;
  const float4* xr = (const float4*)(x + (size_t)row * 768);
  float4 v[3];
  float sum = 0.f, sq = 0.f;
#pragma unroll
  for (int t = 0; t < 3; ++t) {
    v[t] = xr[lane + 64 * t];
    sum += v[t].x + v[t].y + v[t].z + v[t].w;
    sq  += v[t].x * v[t].x + v[t].y * v[t].y + v[t].z * v[t].z + v[t].w * v[t].w;
  }
#pragma unroll
  for (int o = 1; o < 64; o <<= 1) { sum += __shfl_xor(sum, o, 64); sq += __shfl_xor(sq, o, 64); }
  const float mean = sum * (1.f / 768.f);
  const float inv = rsqrtf(sq * (1.f / 768.f) - mean * mean + 1e-5f);
  u16* orow = out + (size_t)row * 768;
#pragma unroll
  for (int t = 0; t < 3; ++t) {
    const int c = 4 * (lane + 64 * t);
    ushort4 o4;
    o4.x = f2bf((v[t].x - mean) * inv * w[c + 0] + bvec[c + 0]);
    o4.y = f2bf((v[t].y - mean) * inv * w[c + 1] + bvec[c + 1]);
    o4.z = f2bf((v[t].z - mean) * inv * w[c + 2] + bvec[c + 2]);
    o4.w = f2bf((v[t].w - mean) * inv * w[c + 3] + bvec[c + 3]);
    *(ushort4*)(orow + c) = o4;
  }
}

// ---------------- GEMM: 128x128 tile, BK=64, 8 waves (64x32 each), 2 blocks/CU --------
// out[M][N] = act(A[M][K](bf16) @ B[N][K]^T(bf16) + bias) [+res]
// LDS: 2 slots x (A[128][64] + B[128][64]) bf16 = 64KB -> 2 blocks/CU (the R4 lever).
// Swizzle: granule gr of row r holds k-chunk gr^(r&7), applied on global src AND
// ds_read (zero bank conflicts, proven R5/R6).
// Per K-tile: 12 ds_read_b128 -> lgkmcnt(0) -> barrier -> stage kt+2 (4 gloads, same
// slot as kt: reads are done) -> counted vmcnt(4) (kt+1 landed, kt+2 in flight) ->
// setprio + 16 MFMA -> barrier.  Two independent blocks/CU interleave the phases.
template <int OUTF32, int ACT, int RES>
__global__ __launch_bounds__(512, 4) void gemm128_k(
    const u16* __restrict__ A, const u16* __restrict__ Bw,
    const float* __restrict__ bias, const float* __restrict__ res,
    void* __restrict__ out, int M, int N, int K, int nbx) {
  __shared__ u16 lds[32768];   // 2 slots x 16384 u16
  const int tid = threadIdx.x;
  const int lane = tid & 63;
  const int wv = tid >> 6;
  const int wr = wv >> 2, wc = wv & 3;   // wave tile: 64(M) x 32(N)

  // bijective XCD swizzle (m204 form), m-outer
  const int nwg = gridDim.x;
  const int q8 = nwg >> 3, r8 = nwg & 7;
  const int xcd = blockIdx.x & 7, cidx = blockIdx.x >> 3;
  const int wg = (xcd < r8 ? xcd * (q8 + 1) : r8 * (q8 + 1) + (xcd - r8) * q8) + cidx;
  const int m0 = (wg / nbx) * 128;
  const int n0 = (wg % nbx) * 128;

  const int frow = lane & 15, fq = lane >> 4;
  const int e = frow & 7;
  // ds_read bases (u16 idx): kk=0 chunk fq -> granule fq^e; kk=1 -> ^32 (chunk+4)
  const int aB0 = (wr * 64 + frow) * 64 + ((fq ^ e) * 8);
  const int bB0 = 8192 + (wc * 32 + frow) * 64 + ((fq ^ e) * 8);

  // staging: thread tid -> granule (tid&7) of row (tid>>3) of a 64-row half
  const int srow = tid >> 3;
  const int cOff = ((tid & 7) ^ (srow & 7)) * 8;
  const u16* pA = A + (size_t)(m0 + srow) * K + cOff;
  const u16* pB = Bw + (size_t)(n0 + srow) * K + cOff;
  const size_t hk = (size_t)K * 64;   // half-tile row span in elems
  const int ldsW = wv * 512;          // wave-uniform dest; HW adds lane*16B

#define LD(IDX) (*(const v8bf*)&lds[IDX])
#define BAR() asm volatile("s_barrier" ::: "memory")
#define VM4() asm volatile("s_waitcnt vmcnt(4)" ::: "memory")
#define VM0() asm volatile("s_waitcnt vmcnt(0)" ::: "memory")
#define STA(kt) do { gload16(pA + (size_t)(kt) * 64, &lds[(((kt) & 1) << 14) + ldsW]); \
                     gload16(pA + hk + (size_t)(kt) * 64, &lds[(((kt) & 1) << 14) + 4096 + ldsW]); } while (0)
#define STB(kt) do { gload16(pB + (size_t)(kt) * 64, &lds[(((kt) & 1) << 14) + 8192 + ldsW]); \
                     gload16(pB + hk + (size_t)(kt) * 64, &lds[(((kt) & 1) << 14) + 12288 + ldsW]); } while (0)

  v4f acc[4][2];
#pragma unroll
  for (int i = 0; i < 4; ++i)
#pragma unroll
    for (int j = 0; j < 2; ++j) acc[i][j] = (v4f){0.f, 0.f, 0.f, 0.f};

  const int NT = K >> 6;   // 12 or 48 K-tiles

  // prologue: stage tiles 0,1; wait tile 0 (tile 1's 4 stay in flight)
  STA(0); STB(0);
  STA(1); STB(1);
  VM4(); BAR();

#define ITER(kt, STG, VM)                                                       \
  do {                                                                          \
    const int sb = ((kt) & 1) << 14;                                            \
    v8bf a0 = LD(sb + aB0), a1 = LD(sb + aB0 + 1024);                           \
    v8bf a2 = LD(sb + aB0 + 2048), a3 = LD(sb + aB0 + 3072);                    \
    v8bf b0 = LD(sb + bB0), b1 = LD(sb + bB0 + 1024);                           \
    v8bf a4 = LD(sb + (aB0 ^ 32)), a5 = LD(sb + (aB0 ^ 32) + 1024);             \
    v8bf a6 = LD(sb + (aB0 ^ 32) + 2048), a7 = LD(sb + (aB0 ^ 32) + 3072);      \
    v8bf b2 = LD(sb + (bB0 ^ 32)), b3 = LD(sb + (bB0 ^ 32) + 1024);             \
    asm volatile("s_waitcnt lgkmcnt(0)" ::: "memory");                          \
    BAR();  /* all waves done reading slot kt -> safe to overwrite */           \
    if (STG) { STA((kt) + 2); STB((kt) + 2); }                                  \
    if ((VM) == 4) VM4(); else if ((VM) == 0) VM0();                            \
    __builtin_amdgcn_s_setprio(1);                                              \
    acc[0][0] = MF(a0, b0, acc[0][0]); acc[0][1] = MF(a0, b1, acc[0][1]);       \
    acc[1][0] = MF(a1, b0, acc[1][0]); acc[1][1] = MF(a1, b1, acc[1][1]);       \
    acc[2][0] = MF(a2, b0, acc[2][0]); acc[2][1] = MF(a2, b1, acc[2][1]);       \
    acc[3][0] = MF(a3, b0, acc[3][0]); acc[3][1] = MF(a3, b1, acc[3][1]);       \
    acc[0][0] = MF(a4, b2, acc[0][0]); acc[0][1] = MF(a4, b3, acc[0][1]);       \
    acc[1][0] = MF(a5, b2, acc[1][0]); acc[1][1] = MF(a5, b3, acc[1][1]);       \
    acc[2][0] = MF(a6, b2, acc[2][0]); acc[2][1] = MF(a6, b3, acc[2][1]);       \
    acc[3][0] = MF(a7, b2, acc[3][0]); acc[3][1] = MF(a7, b3, acc[3][1]);       \
    __builtin_amdgcn_s_setprio(0);                                              \
    BAR();  /* all waves passed vmcnt -> slot (kt+1) fully staged */            \
  } while (0)

  for (int kt = 0; kt < NT - 2; ++kt) ITER(kt, 1, 4);
  ITER(NT - 2, 0, 0);
  ITER(NT - 1, 0, -1);
#undef ITER
#undef LD
#undef BAR
#undef VM4
#undef VM0
#undef STA
#undef STB

  // epilogue: C/D layout col=lane&15, row=(lane>>4)*4+rr
#pragma unroll
  for (int i = 0; i < 4; ++i) {
    const int rowb = m0 + wr * 64 + i * 16 + fq * 4;
#pragma unroll
    for (int j = 0; j < 2; ++j) {
      const int col = n0 + wc * 32 + j * 16 + frow;
      const float bv = bias[col];
#pragma unroll
      for (int rr = 0; rr < 4; ++rr) {
        float v = acc[i][j][rr] + bv;
        if (ACT) v = v * (1.f / (1.f + __expf(-1.702f * v)));  // QuickGELU
        const size_t off = (size_t)(rowb + rr) * N + col;
        if (RES) v += res[off];
        if (OUTF32) ((float*)out)[off] = v;
        else ((u16*)out)[off] = f2bf(v);
      }
    }
  }
}

// ---------------- attention: one block per (b,h); S=77 padded to 80 ----------------
__global__ __launch_bounds__(256) void attn_k(const u16* __restrict__ qkv, u16* __restrict__ ctx) {
  __shared__ u16 sQK[10240];        // sQ[80][64] @0, sK[80][64] @5120; later reused as sP[80][96]
  __shared__ u16 sVt[64 * 120];     // V transposed [d][k], stride 120
  __shared__ float sS[80][81];      // scores fp32
  const int tid = threadIdx.x;
  const int lane = tid & 63;
  const int wv = tid >> 6;
  const int b = blockIdx.x / 12;
  const int h = blockIdx.x % 12;
  u16* sQ = sQK;
  u16* sK = sQK + 5120;
  u16* sP = sQK;

  for (int i = tid; i < 10240 + 64 * 120; i += 256) {
    if (i < 10240) sQK[i] = 0; else sVt[i - 10240] = 0;
  }
  __syncthreads();

  const size_t tokBase = (size_t)(b * 77) * 2304 + h * 64;
  for (int c = tid; c < 77 * 8; c += 256) {
    const int row = c >> 3, k8 = (c & 7) * 8;
    const size_t src = tokBase + (size_t)row * 2304 + k8;
    *(u16x8*)&sQ[row * 64 + k8] = *(const u16x8*)&qkv[src];
    *(u16x8*)&sK[row * 64 + k8] = *(const u16x8*)&qkv[src + 768];
    u16x8 v = *(const u16x8*)&qkv[src + 1536];
#pragma unroll
    for (int j = 0; j < 8; ++j) sVt[(k8 + j) * 120 + row] = v[j];
  }
  __syncthreads();

  const int frow = lane & 15, fk = (lane >> 4) * 8;
  for (int t = wv; t < 25; t += 4) {
    const int it = t / 5, jt = t % 5;
    v4f acc = {0.f, 0.f, 0.f, 0.f};
#pragma unroll
    for (int kk = 0; kk < 2; ++kk) {
      v8bf a = *(const v8bf*)&sQ[(it * 16 + frow) * 64 + kk * 32 + fk];
      v8bf bb = *(const v8bf*)&sK[(jt * 16 + frow) * 64 + kk * 32 + fk];
      acc = MF(a, bb, acc);
    }
    const int col = jt * 16 + frow;
#pragma unroll
    for (int r = 0; r < 4; ++r) {
      const int row = it * 16 + (lane >> 4) * 4 + r;
      sS[row][col] = (col > row) ? -1e30f : acc[r];
    }
  }
  __syncthreads();

  if (tid < 80) {
    const int row = tid;
    float mx = -1e30f;
    for (int c2 = 0; c2 < 80; ++c2) mx = fmaxf(mx, sS[row][c2]);
    float sum = 0.f;
    for (int c2 = 0; c2 < 80; ++c2) { float e = __expf(sS[row][c2] - mx); sum += e; sS[row][c2] = e; }
    const float inv = 1.f / sum;
    for (int c2 = 0; c2 < 80; ++c2) sP[row * 96 + c2] = f2bf(sS[row][c2] * inv);
    for (int c2 = 80; c2 < 96; ++c2) sP[row * 96 + c2] = 0;
  }
  __syncthreads();

  const size_t outBase = (size_t)(b * 77) * 768 + h * 64;
  for (int t = wv; t < 20; t += 4) {
    const int it = t / 4, jt = t % 4;
    v4f acc = {0.f, 0.f, 0.f, 0.f};
#pragma unroll
    for (int kk = 0; kk < 3; ++kk) {
      v8bf a = *(const v8bf*)&sP[(it * 16 + frow) * 96 + kk * 32 + fk];
      v8bf bb = *(const v8bf*)&sVt[(jt * 16 + frow) * 120 + kk * 32 + fk];
      acc = MF(a, bb, acc);
    }
    const int col = jt * 16 + frow;
#pragma unroll
    for (int r = 0; r < 4; ++r) {
      const int row = it * 16 + (lane >> 4) * 4 + r;
      if (row < 77) ctx[outBase + (size_t)row * 768 + col] = f2bf(acc[r]);
    }
  }
}

// ---------------- launch ----------------
extern "C" void kernel_launch(void* const* d_in, const int* in_sizes, int n_in,
                              void* d_out, int out_size, void* d_ws, size_t ws_size,
                              hipStream_t stream) {
  const float* x    = (const float*)d_in[0];
  const float* ln1w = (const float*)d_in[1];
  const float* ln1b = (const float*)d_in[2];
  const float* qw   = (const float*)d_in[3];
  const float* qb   = (const float*)d_in[4];
  const float* kw   = (const float*)d_in[5];
  const float* kb   = (const float*)d_in[6];
  const float* vw   = (const float*)d_in[7];
  const float* vb   = (const float*)d_in[8];
  const float* ow   = (const float*)d_in[9];
  const float* ob   = (const float*)d_in[10];
  const float* ln2w = (const float*)d_in[11];
  const float* ln2b = (const float*)d_in[12];
  const float* f1wf = (const float*)d_in[13];
  const float* f1b  = (const float*)d_in[14];
  const float* f2wf = (const float*)d_in[15];
  const float* f2b  = (const float*)d_in[16];
  float* outp = (float*)d_out;

  char* p = (char*)d_ws;
  auto alloc = [&](size_t bytes) { char* r = p; p += (bytes + 255) & ~(size_t)255; return r; };
  u16* wqkv = (u16*)alloc((size_t)2304 * 768 * 2);   // rows: qw*0.125 | kw | vw
  u16* owb  = (u16*)alloc((size_t)768 * 768 * 2);
  u16* f1w  = (u16*)alloc((size_t)3072 * 768 * 2);
  u16* f2w  = (u16*)alloc((size_t)768 * 3072 * 2);
  float* qkvb = (float*)alloc(2304 * 4);
  u16* bufA = (u16*)alloc((size_t)M_TOK * 768 * 2);   // h -> ctx -> h2in
  u16* bufB = (u16*)alloc((size_t)M_TOK * 3072 * 2);  // qkv (2304 cols) -> h2 (3072 cols)

  cvt4_k<<<576, 256, 0, stream>>>(qw, wqkv, 147456, 0.125f);
  cvt4_k<<<576, 256, 0, stream>>>(kw, wqkv + 589824, 147456, 1.f);
  cvt4_k<<<576, 256, 0, stream>>>(vw, wqkv + 1179648, 147456, 1.f);
  cvt4_k<<<576, 256, 0, stream>>>(ow, owb, 147456, 1.f);
  cvt4_k<<<2304, 256, 0, stream>>>(f1wf, f1w, 589824, 1.f);
  cvt4_k<<<2304, 256, 0, stream>>>(f2wf, f2w, 589824, 1.f);
  qkvb_k<<<9, 256, 0, stream>>>(qb, kb, vb, qkvb);

  ln_k<<<M_TOK / 4, 256, 0, stream>>>(x, ln1w, ln1b, bufA, M_TOK);
  gemm128_k<0, 0, 0><<<308 * 18, 512, 0, stream>>>(bufA, wqkv, qkvb, nullptr, bufB, M_TOK, 2304, 768, 18);
  attn_k<<<512 * 12, 256, 0, stream>>>(bufB, bufA);
  gemm128_k<1, 0, 1><<<308 * 6, 512, 0, stream>>>(bufA, owb, ob, x, outp, M_TOK, 768, 768, 6);
  ln_k<<<M_TOK / 4, 256, 0, stream>>>(outp, ln2w, ln2b, bufA, M_TOK);
  gemm128_k<0, 1, 0><<<308 * 24, 512, 0, stream>>>(bufA, f1w, f1b, nullptr, bufB, M_TOK, 3072, 768, 24);
  gemm128_k<1, 0, 1><<<308 * 6, 512, 0, stream>>>(bufB, f2w, f2b, outp, outp, M_TOK, 768, 3072, 6);
}

// Round 8
// 940.689 us; speedup vs baseline: 1.0124x; 1.0124x over previous
//
#include <hip/hip_runtime.h>

typedef unsigned short u16;
typedef __bf16 v8bf __attribute__((ext_vector_type(8)));
typedef unsigned short u16x8 __attribute__((ext_vector_type(8)));
typedef float v4f __attribute__((ext_vector_type(4)));

#define DEV __device__ __forceinline__

constexpr int M_TOK = 512 * 77;   // 39424 = 128*308

DEV u16 f2bf(float f) {
  union { float f; unsigned int u; } v; v.f = f;
  unsigned int r = v.u + 0x7fffu + ((v.u >> 16) & 1u);
  return (u16)(r >> 16);
}

DEV void gload16(const void* g, void* l) {
  __builtin_amdgcn_global_load_lds((const __attribute__((address_space(1))) void*)g,
                                   (__attribute__((address_space(3))) void*)l, 16, 0, 0);
}

DEV v4f MF(v8bf a, v8bf b, v4f c) {
  return __builtin_amdgcn_mfma_f32_16x16x32_bf16(a, b, c, 0, 0, 0);
}

// ---------------- fp32 -> bf16 convert (x4 vectorized), optional scale ----------------
__global__ void cvt4_k(const float* __restrict__ src, u16* __restrict__ dst, int n4, float scale) {
  int i = blockIdx.x * blockDim.x + threadIdx.x;
  if (i >= n4) return;
  const float4 v = ((const float4*)src)[i];
  ushort4 o;
  o.x = f2bf(v.x * scale); o.y = f2bf(v.y * scale);
  o.z = f2bf(v.z * scale); o.w = f2bf(v.w * scale);
  ((ushort4*)dst)[i] = o;
}

__global__ void qkvb_k(const float* __restrict__ qb, const float* __restrict__ kb,
                       const float* __restrict__ vb, float* __restrict__ dst) {
  int i = blockIdx.x * 256 + threadIdx.x;
  if (i >= 2304) return;
  dst[i] = (i < 768) ? qb[i] * 0.125f : (i < 1536 ? kb[i - 768] : vb[i - 1536]);
}

// ---------------- LayerNorm: one wave per row of 768, writes bf16 ----------------
__global__ __launch_bounds__(256) void ln_k(const float* __restrict__ x, const float* __restrict__ w,
                                            const float* __restrict__ bvec, u16* __restrict__ out, int nrows) {
  const int lane = threadIdx.x & 63;
  const int row = blockIdx.x * 4 + (threadIdx.x >> 6);
  if (row >= nrows) return;
  const float4* xr = (const float4*)(x + (size_t)row * 768);
  float4 v[3];
  float sum = 0.f, sq = 0.f;
#pragma unroll
  for (int t = 0; t < 3; ++t) {
    v[t] = xr[lane + 64 * t];
    sum += v[t].x + v[t].y + v[t].z + v[t].w;
    sq  += v[t].x * v[t].x + v[t].y * v[t].y + v[t].z * v[t].z + v[t].w * v[t].w;
  }
#pragma unroll
  for (int o = 1; o < 64; o <<= 1) { sum += __shfl_xor(sum, o, 64); sq += __shfl_xor(sq, o, 64); }
  const float mean = sum * (1.f / 768.f);
  const float inv = rsqrtf(sq * (1.f / 768.f) - mean * mean + 1e-5f);
  u16* orow = out + (size_t)row * 768;
#pragma unroll
  for (int t = 0; t < 3; ++t) {
    const int c = 4 * (lane + 64 * t);
    ushort4 o4;
    o4.x = f2bf((v[t].x - mean) * inv * w[c + 0] + bvec[c + 0]);
    o4.y = f2bf((v[t].y - mean) * inv * w[c + 1] + bvec[c + 1]);
    o4.z = f2bf((v[t].z - mean) * inv * w[c + 2] + bvec[c + 2]);
    o4.w = f2bf((v[t].w - mean) * inv * w[c + 3] + bvec[c + 3]);
    *(ushort4*)(orow + c) = o4;
  }
}

// ---------------- GEMM: 128x128 tile, BK=64, 4 waves (64x64 each), 2 blocks/CU --------
// out[M][N] = act(A[M][K](bf16) @ B[N][K]^T(bf16) + bias) [+res]
// Wave tile 64x64: 512 B LDS-read per MFMA (vs 768 at 64x32) -> LDS 1506 cyc/K-tile/CU
// vs MFMA 1242 -> ~82% ceiling. LDS: 2 slots x (A[128][64]+B[128][64]) = 64KB -> 2 blk/CU.
// Swizzle: granule g of row r holds k-chunk g^(r&7) on global src AND ds_read (0 conflicts).
// Per K-tile: 16 ds_read_b128 -> lgkm(0) -> barrier -> stage kt+2 (8 gloads, slot just
// freed) -> vmcnt(8) (kt+1 landed) -> setprio + 32 MFMA -> barrier.
template <int OUTF32, int ACT, int RES>
__global__ __launch_bounds__(256, 2) void gemm128_k(
    const u16* __restrict__ A, const u16* __restrict__ Bw,
    const float* __restrict__ bias, const float* __restrict__ res,
    void* __restrict__ out, int M, int N, int K, int nbx) {
  __shared__ u16 lds[32768];   // 2 slots x 16384 u16 (A 8192 + B 8192)
  const int tid = threadIdx.x;
  const int lane = tid & 63;
  const int wv = tid >> 6;
  const int wr = wv >> 1, wc = wv & 1;   // wave tile: 64(M) x 64(N)

  // bijective XCD swizzle (m204 form), m-outer
  const int nwg = gridDim.x;
  const int q8 = nwg >> 3, r8 = nwg & 7;
  const int xcd = blockIdx.x & 7, cidx = blockIdx.x >> 3;
  const int wg = (xcd < r8 ? xcd * (q8 + 1) : r8 * (q8 + 1) + (xcd - r8) * q8) + cidx;
  const int m0 = (wg / nbx) * 128;
  const int n0 = (wg % nbx) * 128;

  const int frow = lane & 15, fq = lane >> 4;
  const int e = frow & 7;
  // ds_read bases (u16 idx): kk=0 chunk fq -> granule fq^e; kk=1 chunk fq+4 -> base^32
  const int aB0 = (wr * 64 + frow) * 64 + ((fq ^ e) * 8);
  const int bB0 = 8192 + (wc * 64 + frow) * 64 + ((fq ^ e) * 8);

  // staging: instr g covers rows g*32..g*32+31; thread: row g*32+(tid>>3), granule tid&7
  const int srow = tid >> 3;                        // 0..31
  const int cOff = ((tid & 7) ^ (srow & 7)) * 8;    // pre-swizzled global chunk
  const u16* pA = A + (size_t)(m0 + srow) * K + cOff;
  const u16* pB = Bw + (size_t)(n0 + srow) * K + cOff;
  const size_t K32 = (size_t)K * 32;   // 32-row span
  const int ldsW = wv * 512;           // wave-uniform; HW adds lane*16B

#define LD(IDX) (*(const v8bf*)&lds[IDX])
#define BAR() asm volatile("s_barrier" ::: "memory")
#define VM8() asm volatile("s_waitcnt vmcnt(8)" ::: "memory")
#define VM0() asm volatile("s_waitcnt vmcnt(0)" ::: "memory")
#define STA(kt) do { const int sb_ = ((kt) & 1) << 14;                              \
    gload16(pA + 0 * K32 + (size_t)(kt) * 64, &lds[sb_ + 0 * 2048 + ldsW]);         \
    gload16(pA + 1 * K32 + (size_t)(kt) * 64, &lds[sb_ + 1 * 2048 + ldsW]);         \
    gload16(pA + 2 * K32 + (size_t)(kt) * 64, &lds[sb_ + 2 * 2048 + ldsW]);         \
    gload16(pA + 3 * K32 + (size_t)(kt) * 64, &lds[sb_ + 3 * 2048 + ldsW]); } while (0)
#define STB(kt) do { const int sb_ = (((kt) & 1) << 14) + 8192;                     \
    gload16(pB + 0 * K32 + (size_t)(kt) * 64, &lds[sb_ + 0 * 2048 + ldsW]);         \
    gload16(pB + 1 * K32 + (size_t)(kt) * 64, &lds[sb_ + 1 * 2048 + ldsW]);         \
    gload16(pB + 2 * K32 + (size_t)(kt) * 64, &lds[sb_ + 2 * 2048 + ldsW]);         \
    gload16(pB + 3 * K32 + (size_t)(kt) * 64, &lds[sb_ + 3 * 2048 + ldsW]); } while (0)

  v4f acc[4][4];
#pragma unroll
  for (int i = 0; i < 4; ++i)
#pragma unroll
    for (int j = 0; j < 4; ++j) acc[i][j] = (v4f){0.f, 0.f, 0.f, 0.f};

  const int NT = K >> 6;   // 12 or 48 K-tiles

  // prologue: stage tiles 0,1; wait tile 0 (tile 1's 8 stay in flight)
  STA(0); STB(0);
  STA(1); STB(1);
  VM8(); BAR();

#define ITER(kt, STG, VM)                                                       \
  do {                                                                          \
    const int sb = ((kt) & 1) << 14;                                            \
    v8bf a0 = LD(sb + aB0), a1 = LD(sb + aB0 + 1024);                           \
    v8bf a2 = LD(sb + aB0 + 2048), a3 = LD(sb + aB0 + 3072);                    \
    v8bf a4 = LD(sb + (aB0 ^ 32)), a5 = LD(sb + (aB0 ^ 32) + 1024);             \
    v8bf a6 = LD(sb + (aB0 ^ 32) + 2048), a7 = LD(sb + (aB0 ^ 32) + 3072);      \
    v8bf b0 = LD(sb + bB0), b1 = LD(sb + bB0 + 1024);                           \
    v8bf b2 = LD(sb + bB0 + 2048), b3 = LD(sb + bB0 + 3072);                    \
    v8bf b4 = LD(sb + (bB0 ^ 32)), b5 = LD(sb + (bB0 ^ 32) + 1024);             \
    v8bf b6 = LD(sb + (bB0 ^ 32) + 2048), b7 = LD(sb + (bB0 ^ 32) + 3072);      \
    asm volatile("s_waitcnt lgkmcnt(0)" ::: "memory");                          \
    BAR();  /* all waves done reading slot kt -> safe to overwrite */           \
    if (STG) { STA((kt) + 2); STB((kt) + 2); }                                  \
    if ((VM) == 8) VM8(); else if ((VM) == 0) VM0();                            \
    __builtin_amdgcn_s_setprio(1);                                              \
    acc[0][0] = MF(a0, b0, acc[0][0]); acc[0][1] = MF(a0, b1, acc[0][1]);       \
    acc[0][2] = MF(a0, b2, acc[0][2]); acc[0][3] = MF(a0, b3, acc[0][3]);       \
    acc[1][0] = MF(a1, b0, acc[1][0]); acc[1][1] = MF(a1, b1, acc[1][1]);       \
    acc[1][2] = MF(a1, b2, acc[1][2]); acc[1][3] = MF(a1, b3, acc[1][3]);       \
    acc[2][0] = MF(a2, b0, acc[2][0]); acc[2][1] = MF(a2, b1, acc[2][1]);       \
    acc[2][2] = MF(a2, b2, acc[2][2]); acc[2][3] = MF(a2, b3, acc[2][3]);       \
    acc[3][0] = MF(a3, b0, acc[3][0]); acc[3][1] = MF(a3, b1, acc[3][1]);       \
    acc[3][2] = MF(a3, b2, acc[3][2]); acc[3][3] = MF(a3, b3, acc[3][3]);       \
    acc[0][0] = MF(a4, b4, acc[0][0]); acc[0][1] = MF(a4, b5, acc[0][1]);       \
    acc[0][2] = MF(a4, b6, acc[0][2]); acc[0][3] = MF(a4, b7, acc[0][3]);       \
    acc[1][0] = MF(a5, b4, acc[1][0]); acc[1][1] = MF(a5, b5, acc[1][1]);       \
    acc[1][2] = MF(a5, b6, acc[1][2]); acc[1][3] = MF(a5, b7, acc[1][3]);       \
    acc[2][0] = MF(a6, b4, acc[2][0]); acc[2][1] = MF(a6, b5, acc[2][1]);       \
    acc[2][2] = MF(a6, b6, acc[2][2]); acc[2][3] = MF(a6, b7, acc[2][3]);       \
    acc[3][0] = MF(a7, b4, acc[3][0]); acc[3][1] = MF(a7, b5, acc[3][1]);       \
    acc[3][2] = MF(a7, b6, acc[3][2]); acc[3][3] = MF(a7, b7, acc[3][3]);       \
    __builtin_amdgcn_s_setprio(0);                                              \
    BAR();  /* all waves passed vmcnt -> slot (kt+1) fully staged */            \
  } while (0)

  for (int kt = 0; kt < NT - 2; ++kt) ITER(kt, 1, 8);
  ITER(NT - 2, 0, 0);
  ITER(NT - 1, 0, -1);
#undef ITER
#undef LD
#undef BAR
#undef VM8
#undef VM0
#undef STA
#undef STB

  // epilogue: C/D layout col=lane&15, row=(lane>>4)*4+rr
#pragma unroll
  for (int i = 0; i < 4; ++i) {
    const int rowb = m0 + wr * 64 + i * 16 + fq * 4;
#pragma unroll
    for (int j = 0; j < 4; ++j) {
      const int col = n0 + wc * 64 + j * 16 + frow;
      const float bv = bias[col];
#pragma unroll
      for (int rr = 0; rr < 4; ++rr) {
        float v = acc[i][j][rr] + bv;
        if (ACT) v = v * (1.f / (1.f + __expf(-1.702f * v)));  // QuickGELU
        const size_t off = (size_t)(rowb + rr) * N + col;
        if (RES) v += res[off];
        if (OUTF32) ((float*)out)[off] = v;
        else ((u16*)out)[off] = f2bf(v);
      }
    }
  }
}

// ---------------- attention: one block per (b,h); S=77 padded to 80 ----------------
__global__ __launch_bounds__(256) void attn_k(const u16* __restrict__ qkv, u16* __restrict__ ctx) {
  __shared__ u16 sQK[10240];        // sQ[80][64] @0, sK[80][64] @5120; later reused as sP[80][96]
  __shared__ u16 sVt[64 * 120];     // V transposed [d][k], stride 120
  __shared__ float sS[80][81];      // scores fp32
  const int tid = threadIdx.x;
  const int lane = tid & 63;
  const int wv = tid >> 6;
  const int b = blockIdx.x / 12;
  const int h = blockIdx.x % 12;
  u16* sQ = sQK;
  u16* sK = sQK + 5120;
  u16* sP = sQK;

  for (int i = tid; i < 10240 + 64 * 120; i += 256) {
    if (i < 10240) sQK[i] = 0; else sVt[i - 10240] = 0;
  }
  __syncthreads();

  const size_t tokBase = (size_t)(b * 77) * 2304 + h * 64;
  for (int c = tid; c < 77 * 8; c += 256) {
    const int row = c >> 3, k8 = (c & 7) * 8;
    const size_t src = tokBase + (size_t)row * 2304 + k8;
    *(u16x8*)&sQ[row * 64 + k8] = *(const u16x8*)&qkv[src];
    *(u16x8*)&sK[row * 64 + k8] = *(const u16x8*)&qkv[src + 768];
    u16x8 v = *(const u16x8*)&qkv[src + 1536];
#pragma unroll
    for (int j = 0; j < 8; ++j) sVt[(k8 + j) * 120 + row] = v[j];
  }
  __syncthreads();

  const int frow = lane & 15, fk = (lane >> 4) * 8;
  for (int t = wv; t < 25; t += 4) {
    const int it = t / 5, jt = t % 5;
    v4f acc = {0.f, 0.f, 0.f, 0.f};
#pragma unroll
    for (int kk = 0; kk < 2; ++kk) {
      v8bf a = *(const v8bf*)&sQ[(it * 16 + frow) * 64 + kk * 32 + fk];
      v8bf bb = *(const v8bf*)&sK[(jt * 16 + frow) * 64 + kk * 32 + fk];
      acc = MF(a, bb, acc);
    }
    const int col = jt * 16 + frow;
#pragma unroll
    for (int r = 0; r < 4; ++r) {
      const int row = it * 16 + (lane >> 4) * 4 + r;
      sS[row][col] = (col > row) ? -1e30f : acc[r];
    }
  }
  __syncthreads();

  if (tid < 80) {
    const int row = tid;
    float mx = -1e30f;
    for (int c2 = 0; c2 < 80; ++c2) mx = fmaxf(mx, sS[row][c2]);
    float sum = 0.f;
    for (int c2 = 0; c2 < 80; ++c2) { float e = __expf(sS[row][c2] - mx); sum += e; sS[row][c2] = e; }
    const float inv = 1.f / sum;
    for (int c2 = 0; c2 < 80; ++c2) sP[row * 96 + c2] = f2bf(sS[row][c2] * inv);
    for (int c2 = 80; c2 < 96; ++c2) sP[row * 96 + c2] = 0;
  }
  __syncthreads();

  const size_t outBase = (size_t)(b * 77) * 768 + h * 64;
  for (int t = wv; t < 20; t += 4) {
    const int it = t / 4, jt = t % 4;
    v4f acc = {0.f, 0.f, 0.f, 0.f};
#pragma unroll
    for (int kk = 0; kk < 3; ++kk) {
      v8bf a = *(const v8bf*)&sP[(it * 16 + frow) * 96 + kk * 32 + fk];
      v8bf bb = *(const v8bf*)&sVt[(jt * 16 + frow) * 120 + kk * 32 + fk];
      acc = MF(a, bb, acc);
    }
    const int col = jt * 16 + frow;
#pragma unroll
    for (int r = 0; r < 4; ++r) {
      const int row = it * 16 + (lane >> 4) * 4 + r;
      if (row < 77) ctx[outBase + (size_t)row * 768 + col] = f2bf(acc[r]);
    }
  }
}

// ---------------- launch ----------------
extern "C" void kernel_launch(void* const* d_in, const int* in_sizes, int n_in,
                              void* d_out, int out_size, void* d_ws, size_t ws_size,
                              hipStream_t stream) {
  const float* x    = (const float*)d_in[0];
  const float* ln1w = (const float*)d_in[1];
  const float* ln1b = (const float*)d_in[2];
  const float* qw   = (const float*)d_in[3];
  const float* qb   = (const float*)d_in[4];
  const float* kw   = (const float*)d_in[5];
  const float* kb   = (const float*)d_in[6];
  const float* vw   = (const float*)d_in[7];
  const float* vb   = (const float*)d_in[8];
  const float* ow   = (const float*)d_in[9];
  const float* ob   = (const float*)d_in[10];
  const float* ln2w = (const float*)d_in[11];
  const float* ln2b = (const float*)d_in[12];
  const float* f1wf = (const float*)d_in[13];
  const float* f1b  = (const float*)d_in[14];
  const float* f2wf = (const float*)d_in[15];
  const float* f2b  = (const float*)d_in[16];
  float* outp = (float*)d_out;

  char* p = (char*)d_ws;
  auto alloc = [&](size_t bytes) { char* r = p; p += (bytes + 255) & ~(size_t)255; return r; };
  u16* wqkv = (u16*)alloc((size_t)2304 * 768 * 2);   // rows: qw*0.125 | kw | vw
  u16* owb  = (u16*)alloc((size_t)768 * 768 * 2);
  u16* f1w  = (u16*)alloc((size_t)3072 * 768 * 2);
  u16* f2w  = (u16*)alloc((size_t)768 * 3072 * 2);
  float* qkvb = (float*)alloc(2304 * 4);
  u16* bufA = (u16*)alloc((size_t)M_TOK * 768 * 2);   // h -> ctx -> h2in
  u16* bufB = (u16*)alloc((size_t)M_TOK * 3072 * 2);  // qkv (2304 cols) -> h2 (3072 cols)

  cvt4_k<<<576, 256, 0, stream>>>(qw, wqkv, 147456, 0.125f);
  cvt4_k<<<576, 256, 0, stream>>>(kw, wqkv + 589824, 147456, 1.f);
  cvt4_k<<<576, 256, 0, stream>>>(vw, wqkv + 1179648, 147456, 1.f);
  cvt4_k<<<576, 256, 0, stream>>>(ow, owb, 147456, 1.f);
  cvt4_k<<<2304, 256, 0, stream>>>(f1wf, f1w, 589824, 1.f);
  cvt4_k<<<2304, 256, 0, stream>>>(f2wf, f2w, 589824, 1.f);
  qkvb_k<<<9, 256, 0, stream>>>(qb, kb, vb, qkvb);

  ln_k<<<M_TOK / 4, 256, 0, stream>>>(x, ln1w, ln1b, bufA, M_TOK);
  gemm128_k<0, 0, 0><<<308 * 18, 256, 0, stream>>>(bufA, wqkv, qkvb, nullptr, bufB, M_TOK, 2304, 768, 18);
  attn_k<<<512 * 12, 256, 0, stream>>>(bufB, bufA);
  gemm128_k<1, 0, 1><<<308 * 6, 256, 0, stream>>>(bufA, owb, ob, x, outp, M_TOK, 768, 768, 6);
  ln_k<<<M_TOK / 4, 256, 0, stream>>>(outp, ln2w, ln2b, bufA, M_TOK);
  gemm128_k<0, 1, 0><<<308 * 24, 256, 0, stream>>>(bufA, f1w, f1b, nullptr, bufB, M_TOK, 3072, 768, 24);
  gemm128_k<1, 0, 1><<<308 * 6, 256, 0, stream>>>(bufB, f2w, f2b, outp, outp, M_TOK, 768, 3072, 6);
}